// Round 4
// baseline (396.982 us; speedup 1.0000x reference)
//
#include <hip/hip_runtime.h>

#define M_TOT 400
#define M_SHOT 100
#define KD 49152
#define DDIM 512
#define KCODE 512

using f16x4  = __attribute__((ext_vector_type(4))) _Float16;
using f16x8  = __attribute__((ext_vector_type(8))) _Float16;
using f32x16 = __attribute__((ext_vector_type(16))) float;

__device__ __forceinline__ unsigned int f2ord(float f) {
    unsigned int u = __float_as_uint(f);
    return (u & 0x80000000u) ? ~u : (u | 0x80000000u);
}

// ---------------- K1: encoder GEMM, f16-limb MFMA ----------------
// Tile 256M x 128N x 1536K-slice, K-step 32. Grid = 2mt * 4ns * 32s = 256 (1 block/CU).
// 8 waves, wave tile 64x64. LDS 96KB static, double-buffered, 1 barrier/step.
// z = 2^-10*(ah*wh) + 2^-21*(ah*wl + al*wh), limbs combined before ONE atomicAdd.
__global__ __launch_bounds__(512, 2)
void k1_gemm(const float* __restrict__ xs, const float* __restrict__ xq,
             const float* __restrict__ W, float* __restrict__ z) {
    __shared__ __align__(16) _Float16 AhS[2][4][256][8];   // 32KB
    __shared__ __align__(16) _Float16 AlS[2][4][256][8];   // 32KB
    __shared__ __align__(16) _Float16 BhS[2][4][128][8];   // 16KB
    __shared__ __align__(16) _Float16 BlS[2][4][128][8];   // 16KB

    const int tid   = threadIdx.x;
    const int lane  = tid & 63;
    const int wv    = tid >> 6;      // 0..7
    const int wm    = wv >> 1;       // 0..3 : 64-row block
    const int wn    = wv & 1;        // 0..1 : 64-col block
    const int l31   = lane & 31;
    const int khalf = lane >> 5;

    // XCD swizzle: the 8 blocks (2mt x 4ns) of one K-slice land on one XCD -> L2 panel reuse
    const int xcd  = blockIdx.x & 7;
    const int u    = blockIdx.x >> 3;        // 0..31
    const int s    = xcd + 8 * (u & 3);      // 0..31 K-slice
    const int tile = u >> 2;                 // 0..7
    const int mt   = tile >> 2;              // 0..1
    const int ns   = tile & 3;               // 0..3
    const int kbase = s * 1536;
    const int mblk  = mt * 256;
    const int nbase = ns * 128;

    // A staging map: 256 rows x 32 k = 2048 float4, 4 per thread
    int aRow[4], aKq[4];
    const float* aPtr[4];
    #pragma unroll
    for (int it = 0; it < 4; it++) {
        int f = tid + it * 512;
        aRow[it] = f >> 3;
        aKq[it]  = (f & 7) << 2;
        int gr = mblk + aRow[it];
        aPtr[it] = (gr < M_TOT)
            ? ((gr < M_SHOT) ? xs + (size_t)gr * KD : xq + (size_t)(gr - M_SHOT) * KD)
            : nullptr;
    }
    // B staging map: 4 kslots x 128 cols, 1 task/thread, 8 k-strided dwords
    const int bKs  = tid >> 7;       // 0..3
    const int bCol = tid & 127;
    const float* bBase = W + (size_t)(kbase + bKs * 8) * DDIM + nbase + bCol;

    f32x16 accA[2][2] = {};
    f32x16 accB[2][2] = {};
    float4 av[4];
    float  bv[8];

    // prologue: issue loads for step 0
    #pragma unroll
    for (int it = 0; it < 4; it++)
        av[it] = aPtr[it] ? *(const float4*)(aPtr[it] + kbase + aKq[it])
                          : make_float4(0.f, 0.f, 0.f, 0.f);
    #pragma unroll
    for (int jk = 0; jk < 8; jk++) bv[jk] = bBase[(size_t)jk * DDIM];

    for (int t = 0; t < 48; t++) {
        const int buf = t & 1;
        // ---- convert + LDS write of step t
        #pragma unroll
        for (int it = 0; it < 4; it++) {
            float vvv[4] = {av[it].x, av[it].y, av[it].z, av[it].w};
            f16x4 hh, ll;
            #pragma unroll
            for (int q = 0; q < 4; q++) {
                _Float16 h = (_Float16)vvv[q];
                hh[q] = h;
                ll[q] = (_Float16)((vvv[q] - (float)h) * 2048.0f);
            }
            const int ks = aKq[it] >> 3, h4 = (aKq[it] >> 2) & 1;
            *(f16x4*)&AhS[buf][ks][aRow[it]][h4 * 4] = hh;
            *(f16x4*)&AlS[buf][ks][aRow[it]][h4 * 4] = ll;
        }
        {
            f16x8 hh, ll;
            #pragma unroll
            for (int jk = 0; jk < 8; jk++) {
                float wsc = bv[jk] * 1024.0f;
                _Float16 h = (_Float16)wsc;
                hh[jk] = h;
                ll[jk] = (_Float16)((wsc - (float)h) * 2048.0f);
            }
            *(f16x8*)&BhS[buf][bKs][bCol][0] = hh;
            *(f16x8*)&BlS[buf][bKs][bCol][0] = ll;
        }
        // ---- issue loads for step t+1 (in flight across barrier + MFMA)
        if (t + 1 < 48) {
            const int k0 = kbase + (t + 1) * 32;
            #pragma unroll
            for (int it = 0; it < 4; it++)
                av[it] = aPtr[it] ? *(const float4*)(aPtr[it] + k0 + aKq[it])
                                  : make_float4(0.f, 0.f, 0.f, 0.f);
            const float* bp = bBase + (size_t)(t + 1) * 32 * DDIM;
            #pragma unroll
            for (int jk = 0; jk < 8; jk++) bv[jk] = bp[(size_t)jk * DDIM];
        }
        __syncthreads();
        // ---- compute step t
        __builtin_amdgcn_s_setprio(1);
        #pragma unroll
        for (int kg = 0; kg < 2; kg++) {
            const int kslot = kg * 2 + khalf;
            f16x8 a_h[2], a_l[2], b_h[2], b_l[2];
            #pragma unroll
            for (int i = 0; i < 2; i++) {
                const int row = wm * 64 + i * 32 + l31;
                a_h[i] = *(const f16x8*)&AhS[buf][kslot][row][0];
                a_l[i] = *(const f16x8*)&AlS[buf][kslot][row][0];
            }
            #pragma unroll
            for (int j = 0; j < 2; j++) {
                const int col = wn * 64 + j * 32 + l31;
                b_h[j] = *(const f16x8*)&BhS[buf][kslot][col][0];
                b_l[j] = *(const f16x8*)&BlS[buf][kslot][col][0];
            }
            #pragma unroll
            for (int i = 0; i < 2; i++)
                #pragma unroll
                for (int j = 0; j < 2; j++) {
                    accA[i][j] = __builtin_amdgcn_mfma_f32_32x32x16_f16(a_h[i], b_h[j], accA[i][j], 0, 0, 0);
                    accB[i][j] = __builtin_amdgcn_mfma_f32_32x32x16_f16(a_h[i], b_l[j], accB[i][j], 0, 0, 0);
                    accB[i][j] = __builtin_amdgcn_mfma_f32_32x32x16_f16(a_l[i], b_h[j], accB[i][j], 0, 0, 0);
                }
        }
        __builtin_amdgcn_s_setprio(0);
        // single barrier/step: step t+1 writes buf^1, whose last readers (step t-1)
        // are ordered before this barrier; buf's readers run after it.
    }

    // epilogue: C/D layout col=lane&31, row=(r&3)+8*(r>>2)+4*(lane>>5)
    #pragma unroll
    for (int i = 0; i < 2; i++) {
        const int mb = mblk + wm * 64 + i * 32 + 4 * khalf;
        #pragma unroll
        for (int j = 0; j < 2; j++) {
            const int nc = nbase + wn * 64 + j * 32 + l31;
            #pragma unroll
            for (int r = 0; r < 16; r++) {
                const int m = mb + (r & 3) + 8 * (r >> 2);
                if (m < M_TOT)
                    atomicAdd(&z[(size_t)m * DDIM + nc],
                              accA[i][j][r] * 0x1p-10f + accB[i][j][r] * 0x1p-21f);
            }
        }
    }
}

// ---------------- K2: shots — block-local argmin over ALL codes + proto ----------------
// block bw (0..19) owns shot rows bw*5 .. bw*5+4; thread = one code.
__global__ __launch_bounds__(512) void k_shots(const float* __restrict__ z,
                                               const float* __restrict__ bias,
                                               const float* __restrict__ cb,
                                               float* __restrict__ proton) {
    __shared__ float zsh[5][512];
    __shared__ unsigned long long wmin[5][8];
    __shared__ int sid[5];
    __shared__ float pred[8];
    const int bw   = blockIdx.x;
    const int tid  = threadIdx.x;
    const int lane = tid & 63;
    const int wvv  = tid >> 6;

    for (int i = tid; i < 5 * 512; i += 512)
        zsh[i >> 9][i & 511] = z[(size_t)(bw * 5 + (i >> 9)) * DDIM + (i & 511)] + bias[i & 511];
    __syncthreads();

    const int k = tid;   // code 0..511
    float cn = 0.f, a0 = 0.f, a1 = 0.f, a2 = 0.f, a3 = 0.f, a4 = 0.f;
    #pragma unroll 2
    for (int d = 0; d < 512; d++) {
        float c = cb[(size_t)d * KCODE + k];
        cn = fmaf(c, c, cn);
        a0 = fmaf(zsh[0][d], c, a0);
        a1 = fmaf(zsh[1][d], c, a1);
        a2 = fmaf(zsh[2][d], c, a2);
        a3 = fmaf(zsh[3][d], c, a3);
        a4 = fmaf(zsh[4][d], c, a4);
    }
    float dist[5] = {fmaf(-2.f, a0, cn), fmaf(-2.f, a1, cn), fmaf(-2.f, a2, cn),
                     fmaf(-2.f, a3, cn), fmaf(-2.f, a4, cn)};
    #pragma unroll
    for (int r = 0; r < 5; r++) {
        unsigned long long p = ((unsigned long long)f2ord(dist[r]) << 32) | (unsigned int)k;
        #pragma unroll
        for (int off = 32; off; off >>= 1) {
            unsigned long long q = __shfl_down(p, off);
            if (q < p) p = q;
        }
        if (lane == 0) wmin[r][wvv] = p;
    }
    __syncthreads();
    if (tid < 5) {
        unsigned long long best = wmin[tid][0];
        #pragma unroll
        for (int w = 1; w < 8; w++) if (wmin[tid][w] < best) best = wmin[tid][w];
        sid[tid] = (int)(unsigned int)(best & 0xFFFFFFFFull);
    }
    __syncthreads();

    // proto for this (b,w): mean of the 5 quantized shots, normalized
    const int d = tid;
    float ssum = 0.f;
    #pragma unroll
    for (int ss = 0; ss < 5; ss++) ssum += cb[(size_t)d * KCODE + sid[ss]];
    float p = ssum * 0.2f;
    float nrm = p * p;
    #pragma unroll
    for (int off = 32; off; off >>= 1) nrm += __shfl_down(nrm, off);
    if (lane == 0) pred[wvv] = nrm;
    __syncthreads();
    float tot = pred[0] + pred[1] + pred[2] + pred[3] + pred[4] + pred[5] + pred[6] + pred[7];
    proton[(size_t)bw * 512 + d] = p * rsqrtf(tot);
}

// ---------------- K3: queries — block-local argmin + cosine logits ----------------
// block n (0..299) owns query row M_SHOT+n; thread = one code, then one dim.
__global__ __launch_bounds__(512) void k_query(const float* __restrict__ z,
                                               const float* __restrict__ bias,
                                               const float* __restrict__ cb,
                                               const float* __restrict__ proton,
                                               const float* __restrict__ tempp,
                                               float* __restrict__ out) {
    __shared__ float zsh[512];
    __shared__ unsigned long long wmin[8];
    __shared__ float part[8][6];
    __shared__ int qidx;
    const int n    = blockIdx.x;
    const int bq   = n / 75;
    const int tid  = threadIdx.x;
    const int lane = tid & 63;
    const int wvv  = tid >> 6;

    zsh[tid] = z[(size_t)(M_SHOT + n) * DDIM + tid] + bias[tid];
    __syncthreads();

    float cn = 0.f, a = 0.f;
    #pragma unroll 4
    for (int d = 0; d < 512; d++) {
        float c = cb[(size_t)d * KCODE + tid];
        cn = fmaf(c, c, cn);
        a  = fmaf(zsh[d], c, a);
    }
    unsigned long long p = ((unsigned long long)f2ord(fmaf(-2.f, a, cn)) << 32) | (unsigned int)tid;
    #pragma unroll
    for (int off = 32; off; off >>= 1) {
        unsigned long long q = __shfl_down(p, off);
        if (q < p) p = q;
    }
    if (lane == 0) wmin[wvv] = p;
    __syncthreads();
    if (tid == 0) {
        unsigned long long best = wmin[0];
        #pragma unroll
        for (int w = 1; w < 8; w++) if (wmin[w] < best) best = wmin[w];
        qidx = (int)(unsigned int)(best & 0xFFFFFFFFull);
    }
    __syncthreads();

    const float qd = cb[(size_t)tid * KCODE + qidx];
    float vals[6];
    vals[0] = qd * qd;
    #pragma unroll
    for (int w5 = 0; w5 < 5; w5++)
        vals[1 + w5] = qd * proton[(size_t)(bq * 5 + w5) * 512 + tid];
    #pragma unroll
    for (int j = 0; j < 6; j++) {
        float v = vals[j];
        #pragma unroll
        for (int off = 32; off; off >>= 1) v += __shfl_down(v, off);
        if (lane == 0) part[wvv][j] = v;
    }
    __syncthreads();
    if (tid == 0) {
        float res[6];
        #pragma unroll
        for (int j = 0; j < 6; j++)
            res[j] = part[0][j] + part[1][j] + part[2][j] + part[3][j]
                   + part[4][j] + part[5][j] + part[6][j] + part[7][j];
        const float temp = tempp[0];
        const float rn = rsqrtf(res[0]);
        #pragma unroll
        for (int w5 = 0; w5 < 5; w5++) out[n * 5 + w5] = temp * rn * res[1 + w5];
    }
}

static const void* find_by_size(void* const* d_in, const int* in_sizes, int n_in,
                                long elems) {
    for (int i = 0; i < n_in; i++) {
        long s = in_sizes[i];
        if (s == elems || s == elems * 4) return d_in[i];   // elements or f32 bytes
    }
    return nullptr;
}

extern "C" void kernel_launch(void* const* d_in, const int* in_sizes, int n_in,
                              void* d_out, int out_size, void* d_ws, size_t ws_size,
                              hipStream_t stream) {
    const float* xs   = (const float*)find_by_size(d_in, in_sizes, n_in, 4915200L);
    const float* xq   = (const float*)find_by_size(d_in, in_sizes, n_in, 14745600L);
    const float* W    = (const float*)find_by_size(d_in, in_sizes, n_in, 25165824L);
    const float* bias = (const float*)find_by_size(d_in, in_sizes, n_in, 512L);
    const float* cb   = (const float*)find_by_size(d_in, in_sizes, n_in, 262144L);
    const float* temp = (const float*)find_by_size(d_in, in_sizes, n_in, 1L);
    if (!xs || !xq || !W || !bias || !cb || !temp) {
        xs = (const float*)d_in[0]; xq = (const float*)d_in[1];
        W  = (const float*)d_in[2]; bias = (const float*)d_in[3];
        cb = (const float*)d_in[4]; temp = (const float*)d_in[5];
    }
    float* out = (float*)d_out;

    float* z      = (float*)d_ws;                             // 204800 f32 (819200 B)
    float* proton = (float*)((char*)d_ws + 819200);           // 10240 f32

    hipMemsetAsync(z, 0, 819200, stream);
    k1_gemm<<<256, 512, 0, stream>>>(xs, xq, W, z);
    k_shots<<<20, 512, 0, stream>>>(z, bias, cb, proton);
    k_query<<<300, 512, 0, stream>>>(z, bias, cb, proton, temp, out);
}

// Round 5
// 312.223 us; speedup vs baseline: 1.2715x; 1.2715x over previous
//
#include <hip/hip_runtime.h>

#define M_TOT 400
#define M_SHOT 100
#define KD 49152
#define DDIM 512
#define KCODE 512

using f16x4  = __attribute__((ext_vector_type(4))) _Float16;
using f16x8  = __attribute__((ext_vector_type(8))) _Float16;
using f32x16 = __attribute__((ext_vector_type(16))) float;

__device__ __forceinline__ unsigned int f2ord(float f) {
    unsigned int u = __float_as_uint(f);
    return (u & 0x80000000u) ? ~u : (u | 0x80000000u);
}

// ---------------- K1: encoder GEMM, f16-limb MFMA ----------------
// Tile 128M x 128N x 1536K-slice, K-step 32. Grid = 4mt * 4ns * 32s = 512 (2 blocks/CU).
// LDS 64KB double-buffered. Pipeline order per step:
//   [convert+LDS-write t] -> barrier -> [ISSUE loads t+1] -> [MFMA t]
// so no global load is ever drained by the vmcnt(0) the compiler puts before s_barrier;
// load latency hides under the MFMA block. A-writes XOR-swizzled (4-way -> 2-way).
__global__ __launch_bounds__(512, 4)
void k1_gemm(const float* __restrict__ xs, const float* __restrict__ xq,
             const float* __restrict__ W, float* __restrict__ z) {
    __shared__ __align__(16) char AhC[16384];                 // [2 buf][4 ks][128 row][16B], swizzled
    __shared__ __align__(16) char AlC[16384];
    __shared__ __align__(16) _Float16 BhS[2][4][128][8];      // 16KB, linear (wave-uniform ks)
    __shared__ __align__(16) _Float16 BlS[2][4][128][8];

    const int tid   = threadIdx.x;
    const int lane  = tid & 63;
    const int wv    = tid >> 6;      // 0..7
    const int wm    = wv >> 2;       // 0..1 : 64-row block
    const int wn    = wv & 3;        // 0..3 : 32-col block
    const int l31   = lane & 31;
    const int khalf = lane >> 5;

    // XCD swizzle: the 16 (mt,ns) blocks of one K-slice land on one XCD.
    // x-slice 2.4MB + W-slice 3MB fit the 4MB per-XCD L2.
    const int xcd  = blockIdx.x & 7;
    const int q    = blockIdx.x >> 3;        // 0..63
    const int s    = xcd + 8 * (q >> 4);     // 0..31 K-slice
    const int tile = q & 15;
    const int mt   = tile >> 2;              // 0..3
    const int ns   = tile & 3;               // 0..3
    const int kbase = s * 1536;
    const int mblk  = mt * 128;
    const int nbase = ns * 128;

    // A byte-offset with XOR swizzle (bank 4-way -> 2-way on ds_write_b64)
    #define AOFF(buf, ks, row, h4) ((buf) * 8192 + (ks) * 2048 + (((row) * 16) ^ ((ks) << 5)) + (h4) * 8)

    // A staging map: 128 rows x 8 k-quads = 1024 float4-tasks, 2 per thread
    int aRow[2], aKq[2];
    const float* aPtr[2];
    #pragma unroll
    for (int it = 0; it < 2; it++) {
        int f = tid + it * 512;
        aRow[it] = f >> 3;
        aKq[it]  = (f & 7) << 2;
        int gr = mblk + aRow[it];
        aPtr[it] = (gr < M_TOT)
            ? ((gr < M_SHOT) ? xs + (size_t)gr * KD : xq + (size_t)(gr - M_SHOT) * KD)
            : nullptr;
    }
    // B staging map: 4 kslots x 128 cols, 1 task/thread, 8 k-strided dwords
    const int bKs  = tid >> 7;       // 0..3
    const int bCol = tid & 127;
    const float* bBase = W + (size_t)(kbase + bKs * 8) * DDIM + nbase + bCol;

    f32x16 accA[2] = {};
    f32x16 accB[2] = {};
    float4 av[2];
    float  bv[8];

    // prologue: issue loads for step 0
    #pragma unroll
    for (int it = 0; it < 2; it++)
        av[it] = aPtr[it] ? *(const float4*)(aPtr[it] + kbase + aKq[it])
                          : make_float4(0.f, 0.f, 0.f, 0.f);
    #pragma unroll
    for (int jk = 0; jk < 8; jk++) bv[jk] = bBase[(size_t)jk * DDIM];

    for (int t = 0; t < 48; t++) {
        const int buf = t & 1;
        // ---- convert + LDS write of step t (compiler inserts the vmcnt wait on av/bv)
        #pragma unroll
        for (int it = 0; it < 2; it++) {
            float vvv[4] = {av[it].x, av[it].y, av[it].z, av[it].w};
            f16x4 hh, ll;
            #pragma unroll
            for (int qq2 = 0; qq2 < 4; qq2++) {
                _Float16 h = (_Float16)vvv[qq2];
                hh[qq2] = h;
                ll[qq2] = (_Float16)((vvv[qq2] - (float)h) * 2048.0f);
            }
            const int ks = aKq[it] >> 3, h4 = (aKq[it] >> 2) & 1;
            *(f16x4*)(AhC + AOFF(buf, ks, aRow[it], h4)) = hh;
            *(f16x4*)(AlC + AOFF(buf, ks, aRow[it], h4)) = ll;
        }
        {
            f16x8 hh, ll;
            #pragma unroll
            for (int jk = 0; jk < 8; jk++) {
                float wsc = bv[jk] * 1024.0f;
                _Float16 h = (_Float16)wsc;
                hh[jk] = h;
                ll[jk] = (_Float16)((wsc - (float)h) * 2048.0f);
            }
            *(f16x8*)&BhS[buf][bKs][bCol][0] = hh;
            *(f16x8*)&BlS[buf][bKs][bCol][0] = ll;
        }
        __syncthreads();
        // ---- issue loads for step t+1 AFTER the barrier: they fly during the MFMAs
        //      and are consumed (convert) before the NEXT barrier -> never drained.
        if (t + 1 < 48) {
            const int k0 = kbase + (t + 1) * 32;
            #pragma unroll
            for (int it = 0; it < 2; it++)
                av[it] = aPtr[it] ? *(const float4*)(aPtr[it] + k0 + aKq[it])
                                  : make_float4(0.f, 0.f, 0.f, 0.f);
            const float* bp = bBase + (size_t)(t + 1) * 32 * DDIM;
            #pragma unroll
            for (int jk = 0; jk < 8; jk++) bv[jk] = bp[(size_t)jk * DDIM];
        }
        // ---- compute step t
        __builtin_amdgcn_s_setprio(1);
        #pragma unroll
        for (int kg = 0; kg < 2; kg++) {
            const int kslot = kg * 2 + khalf;
            f16x8 a_h[2], a_l[2];
            #pragma unroll
            for (int i = 0; i < 2; i++) {
                const int row = wm * 64 + i * 32 + l31;
                a_h[i] = *(const f16x8*)(AhC + AOFF(buf, kslot, row, 0));
                a_l[i] = *(const f16x8*)(AlC + AOFF(buf, kslot, row, 0));
            }
            const int col = wn * 32 + l31;
            f16x8 b_h = *(const f16x8*)&BhS[buf][kslot][col][0];
            f16x8 b_l = *(const f16x8*)&BlS[buf][kslot][col][0];
            #pragma unroll
            for (int i = 0; i < 2; i++) {
                accA[i] = __builtin_amdgcn_mfma_f32_32x32x16_f16(a_h[i], b_h, accA[i], 0, 0, 0);
                accB[i] = __builtin_amdgcn_mfma_f32_32x32x16_f16(a_h[i], b_l, accB[i], 0, 0, 0);
                accB[i] = __builtin_amdgcn_mfma_f32_32x32x16_f16(a_l[i], b_h, accB[i], 0, 0, 0);
            }
        }
        __builtin_amdgcn_s_setprio(0);
        // single barrier/step: step t+1 writes buf^1, whose last readers (MFMA t-1)
        // are ordered before this step's barrier.
    }

    // epilogue: C/D layout col=lane&31, row=(r&3)+8*(r>>2)+4*(lane>>5)
    #pragma unroll
    for (int i = 0; i < 2; i++) {
        const int mb = mblk + wm * 64 + i * 32 + 4 * khalf;
        const int nc = nbase + wn * 32 + l31;
        #pragma unroll
        for (int r = 0; r < 16; r++) {
            const int m = mb + (r & 3) + 8 * (r >> 2);
            if (m < M_TOT)
                atomicAdd(&z[(size_t)m * DDIM + nc],
                          accA[i][r] * 0x1p-10f + accB[i][r] * 0x1p-21f);
        }
    }
    #undef AOFF
}

// ---------------- K2: block-local argmin, 2 rows/block, all 512 codes ----------------
// 200 blocks; thread = one code. No atomics, no init needed.
__global__ __launch_bounds__(512)
void k_argmin(const float* __restrict__ z, const float* __restrict__ bias,
              const float* __restrict__ cb, int* __restrict__ idx) {
    __shared__ float zsh[2][512];
    __shared__ unsigned long long red[2][8];
    const int tid = threadIdx.x, lane = tid & 63, wvv = tid >> 6;
    const int m0 = blockIdx.x * 2;

    for (int i = tid; i < 1024; i += 512)
        zsh[i >> 9][i & 511] = z[(size_t)(m0 + (i >> 9)) * DDIM + (i & 511)] + bias[i & 511];
    __syncthreads();

    float cn = 0.f, a0 = 0.f, a1 = 0.f;
    #pragma unroll 8
    for (int d = 0; d < 512; d++) {
        float c = cb[(size_t)d * KCODE + tid];
        cn = fmaf(c, c, cn);
        a0 = fmaf(zsh[0][d], c, a0);
        a1 = fmaf(zsh[1][d], c, a1);
    }
    unsigned long long p0 = ((unsigned long long)f2ord(fmaf(-2.f, a0, cn)) << 32) | (unsigned int)tid;
    unsigned long long p1 = ((unsigned long long)f2ord(fmaf(-2.f, a1, cn)) << 32) | (unsigned int)tid;
    #pragma unroll
    for (int off = 32; off; off >>= 1) {
        unsigned long long q0 = __shfl_down(p0, off);
        unsigned long long q1 = __shfl_down(p1, off);
        if (q0 < p0) p0 = q0;
        if (q1 < p1) p1 = q1;
    }
    if (lane == 0) { red[0][wvv] = p0; red[1][wvv] = p1; }
    __syncthreads();
    if (tid < 2) {
        unsigned long long best = red[tid][0];
        #pragma unroll
        for (int w = 1; w < 8; w++) if (red[tid][w] < best) best = red[tid][w];
        idx[m0 + tid] = (int)(unsigned int)(best & 0xFFFFFFFFull);
    }
}

// ---------------- K3: per-query logits; protos recomputed locally ----------------
// 300 blocks, one per query; thread = one dim d.
__global__ __launch_bounds__(512)
void k_out(const int* __restrict__ idx, const float* __restrict__ cb,
           const float* __restrict__ tempp, float* __restrict__ out) {
    __shared__ int sidx[25];
    __shared__ float part[8][11];
    const int n    = blockIdx.x;
    const int bq   = n / 75;
    const int tid  = threadIdx.x;
    const int lane = tid & 63;
    const int wvv  = tid >> 6;

    if (tid < 25) sidx[tid] = idx[bq * 25 + tid];
    const int qi = idx[M_SHOT + n];     // uniform broadcast load
    __syncthreads();

    const int d = tid;
    float pr[5];
    #pragma unroll
    for (int w = 0; w < 5; w++) {
        float s5 = 0.f;
        #pragma unroll
        for (int ss = 0; ss < 5; ss++) s5 += cb[(size_t)d * KCODE + sidx[w * 5 + ss]];
        pr[w] = s5 * 0.2f;
    }
    const float qd = cb[(size_t)d * KCODE + qi];

    float vals[11];
    vals[0] = qd * qd;
    #pragma unroll
    for (int w = 0; w < 5; w++) {
        vals[1 + w] = pr[w] * pr[w];
        vals[6 + w] = qd * pr[w];
    }
    #pragma unroll
    for (int j = 0; j < 11; j++) {
        float v = vals[j];
        #pragma unroll
        for (int off = 32; off; off >>= 1) v += __shfl_down(v, off);
        if (lane == 0) part[wvv][j] = v;
    }
    __syncthreads();
    if (tid == 0) {
        float res[11];
        #pragma unroll
        for (int j = 0; j < 11; j++)
            res[j] = part[0][j] + part[1][j] + part[2][j] + part[3][j]
                   + part[4][j] + part[5][j] + part[6][j] + part[7][j];
        const float temp = tempp[0];
        const float rq = rsqrtf(res[0]);
        #pragma unroll
        for (int w = 0; w < 5; w++)
            out[n * 5 + w] = temp * rq * rsqrtf(res[1 + w]) * res[6 + w];
    }
}

static const void* find_by_size(void* const* d_in, const int* in_sizes, int n_in,
                                long elems) {
    for (int i = 0; i < n_in; i++) {
        long s = in_sizes[i];
        if (s == elems || s == elems * 4) return d_in[i];   // elements or f32 bytes
    }
    return nullptr;
}

extern "C" void kernel_launch(void* const* d_in, const int* in_sizes, int n_in,
                              void* d_out, int out_size, void* d_ws, size_t ws_size,
                              hipStream_t stream) {
    const float* xs   = (const float*)find_by_size(d_in, in_sizes, n_in, 4915200L);
    const float* xq   = (const float*)find_by_size(d_in, in_sizes, n_in, 14745600L);
    const float* W    = (const float*)find_by_size(d_in, in_sizes, n_in, 25165824L);
    const float* bias = (const float*)find_by_size(d_in, in_sizes, n_in, 512L);
    const float* cb   = (const float*)find_by_size(d_in, in_sizes, n_in, 262144L);
    const float* temp = (const float*)find_by_size(d_in, in_sizes, n_in, 1L);
    if (!xs || !xq || !W || !bias || !cb || !temp) {
        xs = (const float*)d_in[0]; xq = (const float*)d_in[1];
        W  = (const float*)d_in[2]; bias = (const float*)d_in[3];
        cb = (const float*)d_in[4]; temp = (const float*)d_in[5];
    }
    float* out = (float*)d_out;

    float* z   = (float*)d_ws;                          // 204800 f32 (819200 B)
    int*   idx = (int*)((char*)d_ws + 819200);          // 400 i32

    hipMemsetAsync(z, 0, 819200, stream);
    k1_gemm<<<512, 512, 0, stream>>>(xs, xq, W, z);
    k_argmin<<<200, 512, 0, stream>>>(z, bias, cb, idx);
    k_out<<<300, 512, 0, stream>>>(idx, cb, temp, out);
}